// Round 2
// baseline (971.552 us; speedup 1.0000x reference)
//
#include <hip/hip_runtime.h>

#define NB   16
#define NC   64
#define NPTS 65536
#define RES  32
#define R3   32768
#define PPB  2048   // points per block in reduction kernels (32 blocks/batch)

// ---------------- K1: partial sums for per-batch coord mean ----------------
__global__ void mean_partial(const float* __restrict__ coords, float* __restrict__ meanacc) {
    int bid = blockIdx.x;
    int b = bid >> 5, chunk = bid & 31;
    const float* cb = coords + (size_t)b * 3 * NPTS + chunk * PPB;
    float s0 = 0.f, s1 = 0.f, s2 = 0.f;
    for (int i = threadIdx.x; i < PPB; i += 256) {
        s0 += cb[i];
        s1 += cb[NPTS + i];
        s2 += cb[2 * NPTS + i];
    }
    for (int off = 32; off > 0; off >>= 1) {
        s0 += __shfl_down(s0, off);
        s1 += __shfl_down(s1, off);
        s2 += __shfl_down(s2, off);
    }
    if ((threadIdx.x & 63) == 0) {
        atomicAdd(&meanacc[b * 3 + 0], s0);
        atomicAdd(&meanacc[b * 3 + 1], s1);
        atomicAdd(&meanacc[b * 3 + 2], s2);
    }
}

// ---------------- K2: per-batch max L2 norm (atomicMax on int-reinterpreted float) ----------------
__global__ void maxnorm_partial(const float* __restrict__ coords,
                                const float* __restrict__ meanacc,
                                int* __restrict__ maxn) {
    int bid = blockIdx.x;
    int b = bid >> 5, chunk = bid & 31;
    const float* cb = coords + (size_t)b * 3 * NPTS + chunk * PPB;
    float m0 = meanacc[b * 3 + 0] * (1.0f / NPTS);
    float m1 = meanacc[b * 3 + 1] * (1.0f / NPTS);
    float m2 = meanacc[b * 3 + 2] * (1.0f / NPTS);
    float mx = 0.f;
    for (int i = threadIdx.x; i < PPB; i += 256) {
        float x = cb[i] - m0;
        float y = cb[NPTS + i] - m1;
        float z = cb[2 * NPTS + i] - m2;
        mx = fmaxf(mx, sqrtf(x * x + y * y + z * z));
    }
    for (int off = 32; off > 0; off >>= 1)
        mx = fmaxf(mx, __shfl_down(mx, off));
    if ((threadIdx.x & 63) == 0)
        atomicMax(&maxn[b], __float_as_int(mx));   // norms >= 0: int order == float order
}

// ---------------- K3: normalize coords (2nd output), voxel id, count histogram ----------------
__global__ void voxelize(const float* __restrict__ coords,
                         const float* __restrict__ meanacc,
                         const int* __restrict__ maxn,
                         float* __restrict__ ncout,
                         unsigned short* __restrict__ voxid,
                         unsigned int* __restrict__ cnt) {
    int t = blockIdx.x * 256 + threadIdx.x;
    int b = t >> 16, n = t & (NPTS - 1);
    const float* cb = coords + (size_t)b * 3 * NPTS;
    float m2 = __int_as_float(maxn[b]) * 2.0f;   // EPS = 0
    float c0 = meanacc[b * 3 + 0] * (1.0f / NPTS);
    float c1 = meanacc[b * 3 + 1] * (1.0f / NPTS);
    float c2 = meanacc[b * 3 + 2] * (1.0f / NPTS);
    float ncx = (cb[n]            - c0) / m2 + 0.5f;
    float ncy = (cb[NPTS + n]     - c1) / m2 + 0.5f;
    float ncz = (cb[2 * NPTS + n] - c2) / m2 + 0.5f;
    float sx = fminf(fmaxf(ncx * (float)RES, 0.f), (float)(RES - 1));
    float sy = fminf(fmaxf(ncy * (float)RES, 0.f), (float)(RES - 1));
    float sz = fminf(fmaxf(ncz * (float)RES, 0.f), (float)(RES - 1));
    float* nb = ncout + (size_t)b * 3 * NPTS;
    nb[n]            = sx;
    nb[NPTS + n]     = sy;
    nb[2 * NPTS + n] = sz;
    int v = (((int)rintf(sx)) << 10) + (((int)rintf(sy)) << 5) + (int)rintf(sz);
    voxid[t] = (unsigned short)v;
    atomicAdd(&cnt[((size_t)b << 15) + v], 1u);
}

// ---------------- K4: per-batch exclusive scan of counts -> offsets (+cursor copy) ----------------
__global__ void scan_kernel(const unsigned int* __restrict__ cnt,
                            unsigned int* __restrict__ off,
                            unsigned int* __restrict__ cur) {
    __shared__ unsigned int s[1024];
    int b = blockIdx.x, tid = threadIdx.x;
    const unsigned int* cb = cnt + ((size_t)b << 15);
    int base = tid * 32;
    unsigned int local[32];
    unsigned int sum = 0;
    for (int j = 0; j < 32; ++j) { local[j] = cb[base + j]; sum += local[j]; }
    s[tid] = sum;
    __syncthreads();
    for (int o = 1; o < 1024; o <<= 1) {
        unsigned int t2 = (tid >= o) ? s[tid - o] : 0u;
        __syncthreads();
        s[tid] += t2;
        __syncthreads();
    }
    unsigned int run = s[tid] - sum;   // exclusive base for this thread's chunk
    unsigned int* ob = off + ((size_t)b << 15);
    unsigned int* ub = cur + ((size_t)b << 15);
    for (int j = 0; j < 32; ++j) {
        ob[base + j] = run;
        ub[base + j] = run;
        run += local[j];
    }
}

// ============ PATH A: transpose into voxel-sorted bf16 rows, then per-voxel gather ============

// K5a: coalesced-read a 128-point x 64-ch tile, LDS-transpose, write each point's
// 64-ch row (bf16, 128B contiguous) at its voxel-sorted slot.
__global__ void transpose_scatter(const float* __restrict__ features,
                                  const unsigned short* __restrict__ voxid,
                                  unsigned int* __restrict__ cur,
                                  unsigned short* __restrict__ sortedfeat) { // bf16 rows
    __shared__ float lds[128 * 65];
    __shared__ unsigned int posArr[128];
    int bid = blockIdx.x;                  // 16 * 512 blocks
    int b = bid >> 9;
    int n0 = (bid & 511) << 7;             // 128 points per block
    int pt = threadIdx.x & 127;
    int half = threadIdx.x >> 7;           // 0/1 -> channels 0..31 / 32..63
    const float* fb = features + ((size_t)b << 22) + n0 + pt;
#pragma unroll
    for (int cc = 0; cc < 32; ++cc) {
        int c = (half << 5) + cc;
        lds[pt * 65 + c] = fb[(size_t)c << 16];   // coalesced 512B per (c)
    }
    if (threadIdx.x < 128) {
        int v = voxid[((size_t)b << 16) + n0 + threadIdx.x];
        unsigned int pos = atomicAdd(&cur[((size_t)b << 15) + v], 1u);
        posArr[threadIdx.x] = pos;
    }
    __syncthreads();
    int w = threadIdx.x >> 6;              // 4 waves, 32 points each
    int lane = threadIdx.x & 63;
    for (int p = (w << 5); p < (w << 5) + 32; ++p) {
        unsigned int pos = posArr[p];
        float f = lds[p * 65 + lane];
        unsigned int x = __float_as_uint(f);
        unsigned short h = (unsigned short)((x + 0x7fffu + ((x >> 16) & 1u)) >> 16);  // RNE bf16
        sortedfeat[(((size_t)((b << 16) + pos)) << 6) + lane] = h;
    }
}

// K6a: wave-per-4-voxels gather over the sorted rows. lane = channel.
// Rows of 4 consecutive voxels are contiguous in sortedfeat (off is an
// exclusive scan), so each wave reads one linear row range with a
// statically-unrolled per-voxel split. No atomics, no boundary fixups,
// every grid element written exactly once (grid memset dropped).
__global__ void voxel_mean(const unsigned short* __restrict__ sf,   // bf16 rows
                           const unsigned int* __restrict__ off,
                           const unsigned int* __restrict__ cnt,
                           float* __restrict__ grid) {
    int w = (blockIdx.x * 256 + threadIdx.x) >> 6;   // 131072 waves
    int lane = threadIdx.x & 63;
    int v0 = w << 2;                                 // 4 consecutive voxels
    int b  = v0 >> 15;
    int vv = v0 & (R3 - 1);
    const unsigned int* offb = off + ((size_t)b << 15) + vv;
    const unsigned int* cntb = cnt + ((size_t)b << 15) + vv;
    unsigned int o[4], k[4];
#pragma unroll
    for (int j = 0; j < 4; ++j) { o[j] = offb[j]; k[j] = cntb[j]; }
    const unsigned short* rp = sf + (((size_t)b << 16) << 6) + lane;
    float acc[4];
    unsigned int idx = o[0];
#pragma unroll
    for (int j = 0; j < 4; ++j) {
        float a = 0.f;
        unsigned int e = o[j] + k[j];                // == next offset (contiguous)
        for (; idx < e; ++idx) {
            unsigned int u = rp[(size_t)idx << 6];
            a += __uint_as_float(u << 16);           // bf16 -> f32
        }
        acc[j] = a / fmaxf((float)k[j], 1.0f);
    }
    float* gp = grid + ((size_t)b << 21) + ((size_t)lane << 15) + vv;
    *(float4*)gp = make_float4(acc[0], acc[1], acc[2], acc[3]);
}

// ============ PATH B (fallback, small ws): sorted-index gather with 8-ch ILP ============

__global__ void scatter_ids(const unsigned short* __restrict__ voxid,
                            unsigned int* __restrict__ cur,
                            unsigned short* __restrict__ sorted) {
    int t = blockIdx.x * 256 + threadIdx.x;
    int b = t >> 16, n = t & (NPTS - 1);
    int v = voxid[t];
    unsigned int pos = atomicAdd(&cur[((size_t)b << 15) + v], 1u);
    sorted[((size_t)b << 16) + pos] = (unsigned short)n;
}

__global__ void gather_cpt8(const float* __restrict__ features,
                            const unsigned short* __restrict__ sorted,
                            const unsigned int* __restrict__ off,
                            const unsigned int* __restrict__ cnt,
                            float* __restrict__ grid) {
    int bid = blockIdx.x;
    int xcd = bid & 7;
    int g_  = bid >> 3;
    int chunk = g_ & 127;
    int sgg = g_ >> 7;
    int sg = (sgg << 3) + xcd;
    int b = sg >> 3;
    int c0 = (sg & 7) << 3;
    int v = (chunk << 8) + threadIdx.x;
    size_t bv = ((size_t)b << 15) + v;
    unsigned int base = off[bv];
    unsigned int k = cnt[bv];
    const unsigned short* sp = sorted + ((size_t)b << 16);
    const float* f = features + ((size_t)((b << 6) + c0) << 16);
    float s[8] = {0,0,0,0,0,0,0,0};
    for (unsigned int i = 0; i < k; ++i) {
        int idx = sp[base + i];
#pragma unroll
        for (int j = 0; j < 8; ++j)
            s[j] += f[((size_t)j << 16) + idx];
    }
    float inv = 1.0f / fmaxf((float)k, 1.0f);
#pragma unroll
    for (int j = 0; j < 8; ++j)
        grid[((size_t)((b << 6) + c0 + j) << 15) + v] = s[j] * inv;
}

extern "C" void kernel_launch(void* const* d_in, const int* in_sizes, int n_in,
                              void* d_out, int out_size, void* d_ws, size_t ws_size,
                              hipStream_t stream) {
    const float* features = (const float*)d_in[0];  // [16, 64, 65536]
    const float* coords   = (const float*)d_in[1];  // [16, 3, 65536]

    float* grid  = (float*)d_out;                    // [16, 64, 32768]
    float* ncout = grid + (size_t)NB * NC * R3;      // [16, 3, 65536]

    // ws: meanacc[48] | maxn[16] | pad->256B | cnt 2MB | off 2MB | cur 2MB |
    //     voxid 2MB(u16) | sortedvox 2MB(u16, path B only) | sortedfeat 134MB (bf16 rows)
    char* base = (char*)d_ws;
    float* meanacc = (float*)base;
    int*   maxn    = (int*)(base + 192);
    unsigned int*   cnt       = (unsigned int*)(base + 256);
    unsigned int*   off       = cnt + (size_t)NB * R3;
    unsigned int*   cur       = off + (size_t)NB * R3;
    unsigned short* voxid     = (unsigned short*)(cur + (size_t)NB * R3);
    unsigned short* sortedvox = voxid + (size_t)NB * NPTS;   // Path B point-id list
    const size_t sf_off = 256 + 3 * (size_t)NB * R3 * 4 + 2 * (size_t)NB * NPTS * 2;
    unsigned short* sortedfeat = (unsigned short*)(base + sf_off);
    const bool pathA = ws_size >= sf_off + (size_t)NB * NPTS * NC * sizeof(unsigned short);

    // zero meanacc/maxn/cnt (~2 MB). grid memset no longer needed:
    // voxel_mean (path A) / gather_cpt8 (path B) write every element.
    hipMemsetAsync(d_ws, 0, 256 + (size_t)NB * R3 * sizeof(unsigned int), stream);

    mean_partial   <<<NB * 32, 256, 0, stream>>>(coords, meanacc);
    maxnorm_partial<<<NB * 32, 256, 0, stream>>>(coords, meanacc, maxn);
    voxelize       <<<NB * NPTS / 256, 256, 0, stream>>>(coords, meanacc, maxn, ncout, voxid, cnt);
    scan_kernel    <<<NB, 1024, 0, stream>>>(cnt, off, cur);
    if (pathA) {
        transpose_scatter<<<NB * (NPTS / 128), 256, 0, stream>>>(features, voxid, cur, sortedfeat);
        voxel_mean       <<<NB * R3 / 16, 256, 0, stream>>>(sortedfeat, off, cnt, grid);
    } else {
        scatter_ids<<<NB * NPTS / 256, 256, 0, stream>>>(voxid, cur, sortedvox);
        gather_cpt8<<<(NB * 8) * (R3 / 256), 256, 0, stream>>>(features, sortedvox, off, cnt, grid);
    }
}

// Round 3
// 756.310 us; speedup vs baseline: 1.2846x; 1.2846x over previous
//
#include <hip/hip_runtime.h>

#define NB   16
#define NC   64
#define NPTS 65536
#define RES  32
#define R3   32768
#define PPB  2048   // points per block in reduction kernels (32 blocks/batch)

typedef unsigned short ushort8 __attribute__((ext_vector_type(8)));

// ---------------- K1: partial sums for per-batch coord mean ----------------
__global__ void mean_partial(const float* __restrict__ coords, float* __restrict__ meanacc) {
    int bid = blockIdx.x;
    int b = bid >> 5, chunk = bid & 31;
    const float* cb = coords + (size_t)b * 3 * NPTS + chunk * PPB;
    float s0 = 0.f, s1 = 0.f, s2 = 0.f;
    for (int i = threadIdx.x; i < PPB; i += 256) {
        s0 += cb[i];
        s1 += cb[NPTS + i];
        s2 += cb[2 * NPTS + i];
    }
    for (int off = 32; off > 0; off >>= 1) {
        s0 += __shfl_down(s0, off);
        s1 += __shfl_down(s1, off);
        s2 += __shfl_down(s2, off);
    }
    if ((threadIdx.x & 63) == 0) {
        atomicAdd(&meanacc[b * 3 + 0], s0);
        atomicAdd(&meanacc[b * 3 + 1], s1);
        atomicAdd(&meanacc[b * 3 + 2], s2);
    }
}

// ---------------- K2: per-batch max L2 norm (atomicMax on int-reinterpreted float) ----------------
__global__ void maxnorm_partial(const float* __restrict__ coords,
                                const float* __restrict__ meanacc,
                                int* __restrict__ maxn) {
    int bid = blockIdx.x;
    int b = bid >> 5, chunk = bid & 31;
    const float* cb = coords + (size_t)b * 3 * NPTS + chunk * PPB;
    float m0 = meanacc[b * 3 + 0] * (1.0f / NPTS);
    float m1 = meanacc[b * 3 + 1] * (1.0f / NPTS);
    float m2 = meanacc[b * 3 + 2] * (1.0f / NPTS);
    float mx = 0.f;
    for (int i = threadIdx.x; i < PPB; i += 256) {
        float x = cb[i] - m0;
        float y = cb[NPTS + i] - m1;
        float z = cb[2 * NPTS + i] - m2;
        mx = fmaxf(mx, sqrtf(x * x + y * y + z * z));
    }
    for (int off = 32; off > 0; off >>= 1)
        mx = fmaxf(mx, __shfl_down(mx, off));
    if ((threadIdx.x & 63) == 0)
        atomicMax(&maxn[b], __float_as_int(mx));   // norms >= 0: int order == float order
}

// ---------------- K3: normalize coords (2nd output), voxel id, count histogram ----------------
__global__ void voxelize(const float* __restrict__ coords,
                         const float* __restrict__ meanacc,
                         const int* __restrict__ maxn,
                         float* __restrict__ ncout,
                         unsigned short* __restrict__ voxid,
                         unsigned int* __restrict__ cnt) {
    int t = blockIdx.x * 256 + threadIdx.x;
    int b = t >> 16, n = t & (NPTS - 1);
    const float* cb = coords + (size_t)b * 3 * NPTS;
    float m2 = __int_as_float(maxn[b]) * 2.0f;   // EPS = 0
    float c0 = meanacc[b * 3 + 0] * (1.0f / NPTS);
    float c1 = meanacc[b * 3 + 1] * (1.0f / NPTS);
    float c2 = meanacc[b * 3 + 2] * (1.0f / NPTS);
    float ncx = (cb[n]            - c0) / m2 + 0.5f;
    float ncy = (cb[NPTS + n]     - c1) / m2 + 0.5f;
    float ncz = (cb[2 * NPTS + n] - c2) / m2 + 0.5f;
    float sx = fminf(fmaxf(ncx * (float)RES, 0.f), (float)(RES - 1));
    float sy = fminf(fmaxf(ncy * (float)RES, 0.f), (float)(RES - 1));
    float sz = fminf(fmaxf(ncz * (float)RES, 0.f), (float)(RES - 1));
    float* nb = ncout + (size_t)b * 3 * NPTS;
    nb[n]            = sx;
    nb[NPTS + n]     = sy;
    nb[2 * NPTS + n] = sz;
    int v = (((int)rintf(sx)) << 10) + (((int)rintf(sy)) << 5) + (int)rintf(sz);
    voxid[t] = (unsigned short)v;
    atomicAdd(&cnt[((size_t)b << 15) + v], 1u);
}

// ---------------- K4: per-batch exclusive scan of counts -> offsets (+cursor copy) ----------------
__global__ void scan_kernel(const unsigned int* __restrict__ cnt,
                            unsigned int* __restrict__ off,
                            unsigned int* __restrict__ cur) {
    __shared__ unsigned int s[1024];
    int b = blockIdx.x, tid = threadIdx.x;
    const unsigned int* cb = cnt + ((size_t)b << 15);
    int base = tid * 32;
    unsigned int local[32];
    unsigned int sum = 0;
    for (int j = 0; j < 32; ++j) { local[j] = cb[base + j]; sum += local[j]; }
    s[tid] = sum;
    __syncthreads();
    for (int o = 1; o < 1024; o <<= 1) {
        unsigned int t2 = (tid >= o) ? s[tid - o] : 0u;
        __syncthreads();
        s[tid] += t2;
        __syncthreads();
    }
    unsigned int run = s[tid] - sum;   // exclusive base for this thread's chunk
    unsigned int* ob = off + ((size_t)b << 15);
    unsigned int* ub = cur + ((size_t)b << 15);
    for (int j = 0; j < 32; ++j) {
        ob[base + j] = run;
        ub[base + j] = run;
        run += local[j];
    }
}

// ============ PATH A: transpose into voxel-sorted bf16 rows, then column gather ============

// K5a: coalesced-read a 128-point x 64-ch tile, LDS-transpose, write each point's
// 64-ch row (bf16, 128B contiguous) at its voxel-sorted slot.
__global__ void transpose_scatter(const float* __restrict__ features,
                                  const unsigned short* __restrict__ voxid,
                                  unsigned int* __restrict__ cur,
                                  unsigned short* __restrict__ sortedfeat) { // bf16 rows
    __shared__ float lds[128 * 65];
    __shared__ unsigned int posArr[128];
    int bid = blockIdx.x;                  // 16 * 512 blocks
    int b = bid >> 9;
    int n0 = (bid & 511) << 7;             // 128 points per block
    int pt = threadIdx.x & 127;
    int half = threadIdx.x >> 7;           // 0/1 -> channels 0..31 / 32..63
    const float* fb = features + ((size_t)b << 22) + n0 + pt;
#pragma unroll
    for (int cc = 0; cc < 32; ++cc) {
        int c = (half << 5) + cc;
        lds[pt * 65 + c] = fb[(size_t)c << 16];   // coalesced 512B per (c)
    }
    if (threadIdx.x < 128) {
        int v = voxid[((size_t)b << 16) + n0 + threadIdx.x];
        unsigned int pos = atomicAdd(&cur[((size_t)b << 15) + v], 1u);
        posArr[threadIdx.x] = pos;
    }
    __syncthreads();
    int w = threadIdx.x >> 6;              // 4 waves, 32 points each
    int lane = threadIdx.x & 63;
    for (int p = (w << 5); p < (w << 5) + 32; ++p) {
        unsigned int pos = posArr[p];
        float f = lds[p * 65 + lane];
        unsigned int x = __float_as_uint(f);
        unsigned short h = (unsigned short)((x + 0x7fffu + ((x >> 16) & 1u)) >> 16);  // RNE bf16
        sortedfeat[(((size_t)((b << 16) + pos)) << 6) + lane] = h;
    }
}

// K6a: one wave per (b,x,y) z-column = 32 consecutive voxels = one contiguous
// row range in sortedfeat. lane = (row-slot rg 0..7, ch-group g 0..7): each
// lane loads 16B (8 bf16 ch), wave covers 8 rows (1KB) per iteration with
// independent (pipelineable) loads. Per voxel: shfl_xor butterfly over the 8
// row-slots, stage 64ch result in a per-wave LDS tile, write the 64ch x 32z
// tile as coalesced 128B chunks. Empty columns short-circuit to zero-fill.
__global__ void voxel_mean2(const unsigned short* __restrict__ sf,   // bf16 rows
                            const unsigned int* __restrict__ off,
                            const unsigned int* __restrict__ cnt,
                            float* __restrict__ grid) {
    __shared__ float lds[4][32 * 68];      // per-wave 64ch x 32z tile, pitch 68
    int wv   = threadIdx.x >> 6;
    int lane = threadIdx.x & 63;
    int col  = (blockIdx.x << 2) + wv;     // 16384 columns = 16 b * 1024 (x,y)
    int b    = col >> 10;
    int xy   = col & 1023;
    int vbase = xy << 5;
    const unsigned int* offb = off + ((size_t)b << 15) + vbase;
    const unsigned int* cntb = cnt + ((size_t)b << 15) + vbase;
    int lz = lane & 31;
    unsigned int o_l = offb[lz];           // offsets/counts for the 32 voxels
    unsigned int k_l = cntb[lz];
    float* gb = grid + ((size_t)b << 21) + ((size_t)xy << 5);
    int zq = lane & 7, cg = lane >> 3;

    unsigned int tot = (unsigned int)__shfl((int)(o_l + k_l), 31) -
                       (unsigned int)__shfl((int)o_l, 0);
    if (tot == 0) {                        // fully-empty column -> zero fill
        float4 z4 = make_float4(0.f, 0.f, 0.f, 0.f);
#pragma unroll
        for (int it = 0; it < 8; ++it) {
            int c = (it << 3) + cg;
            *(float4*)(gb + ((size_t)c << 15) + (zq << 2)) = z4;
        }
        return;
    }

    int rg = lane >> 3, g = lane & 7;
    const unsigned short* sfb = sf + ((size_t)b << 22);   // b * 65536 * 64
    float* ldsw = lds[wv];
    for (int z = 0; z < 32; ++z) {
        unsigned int oz = (unsigned int)__shfl((int)o_l, z);
        unsigned int kz = (unsigned int)__shfl((int)k_l, z);
        float a0 = 0.f, a1 = 0.f, a2 = 0.f, a3 = 0.f,
              a4 = 0.f, a5 = 0.f, a6 = 0.f, a7 = 0.f;
        if (kz) {                          // wave-uniform branch
            int iters = (int)((kz + 7u) >> 3);
            for (int j = 0; j < iters; ++j) {
                unsigned int r = (unsigned int)(j << 3) + (unsigned int)rg;
                if (r < kz) {
                    ushort8 u = *(const ushort8*)(sfb + (((size_t)(oz + r)) << 6) + (g << 3));
                    a0 += __uint_as_float((unsigned int)u[0] << 16);
                    a1 += __uint_as_float((unsigned int)u[1] << 16);
                    a2 += __uint_as_float((unsigned int)u[2] << 16);
                    a3 += __uint_as_float((unsigned int)u[3] << 16);
                    a4 += __uint_as_float((unsigned int)u[4] << 16);
                    a5 += __uint_as_float((unsigned int)u[5] << 16);
                    a6 += __uint_as_float((unsigned int)u[6] << 16);
                    a7 += __uint_as_float((unsigned int)u[7] << 16);
                }
            }
#pragma unroll
            for (int m = 8; m < 64; m <<= 1) {   // butterfly over row-slots
                a0 += __shfl_xor(a0, m);
                a1 += __shfl_xor(a1, m);
                a2 += __shfl_xor(a2, m);
                a3 += __shfl_xor(a3, m);
                a4 += __shfl_xor(a4, m);
                a5 += __shfl_xor(a5, m);
                a6 += __shfl_xor(a6, m);
                a7 += __shfl_xor(a7, m);
            }
        }
        if (rg == 0) {
            float inv = 1.0f / fmaxf((float)kz, 1.0f);
            float4 v0 = make_float4(a0 * inv, a1 * inv, a2 * inv, a3 * inv);
            float4 v1 = make_float4(a4 * inv, a5 * inv, a6 * inv, a7 * inv);
            *(float4*)&ldsw[z * 68 + (g << 3)]     = v0;
            *(float4*)&ldsw[z * 68 + (g << 3) + 4] = v1;
        }
    }
    // write 64ch x 32z tile: per channel a contiguous 128B chunk (32 z floats)
#pragma unroll
    for (int it = 0; it < 8; ++it) {
        int c = (it << 3) + cg;
        float4 v = make_float4(ldsw[(zq * 4 + 0) * 68 + c],
                               ldsw[(zq * 4 + 1) * 68 + c],
                               ldsw[(zq * 4 + 2) * 68 + c],
                               ldsw[(zq * 4 + 3) * 68 + c]);
        *(float4*)(gb + ((size_t)c << 15) + (zq << 2)) = v;
    }
}

// ============ PATH B (fallback, small ws): sorted-index gather with 8-ch ILP ============

__global__ void scatter_ids(const unsigned short* __restrict__ voxid,
                            unsigned int* __restrict__ cur,
                            unsigned short* __restrict__ sorted) {
    int t = blockIdx.x * 256 + threadIdx.x;
    int b = t >> 16, n = t & (NPTS - 1);
    int v = voxid[t];
    unsigned int pos = atomicAdd(&cur[((size_t)b << 15) + v], 1u);
    sorted[((size_t)b << 16) + pos] = (unsigned short)n;
}

__global__ void gather_cpt8(const float* __restrict__ features,
                            const unsigned short* __restrict__ sorted,
                            const unsigned int* __restrict__ off,
                            const unsigned int* __restrict__ cnt,
                            float* __restrict__ grid) {
    int bid = blockIdx.x;
    int xcd = bid & 7;
    int g_  = bid >> 3;
    int chunk = g_ & 127;
    int sgg = g_ >> 7;
    int sg = (sgg << 3) + xcd;
    int b = sg >> 3;
    int c0 = (sg & 7) << 3;
    int v = (chunk << 8) + threadIdx.x;
    size_t bv = ((size_t)b << 15) + v;
    unsigned int base = off[bv];
    unsigned int k = cnt[bv];
    const unsigned short* sp = sorted + ((size_t)b << 16);
    const float* f = features + ((size_t)((b << 6) + c0) << 16);
    float s[8] = {0,0,0,0,0,0,0,0};
    for (unsigned int i = 0; i < k; ++i) {
        int idx = sp[base + i];
#pragma unroll
        for (int j = 0; j < 8; ++j)
            s[j] += f[((size_t)j << 16) + idx];
    }
    float inv = 1.0f / fmaxf((float)k, 1.0f);
#pragma unroll
    for (int j = 0; j < 8; ++j)
        grid[((size_t)((b << 6) + c0 + j) << 15) + v] = s[j] * inv;
}

extern "C" void kernel_launch(void* const* d_in, const int* in_sizes, int n_in,
                              void* d_out, int out_size, void* d_ws, size_t ws_size,
                              hipStream_t stream) {
    const float* features = (const float*)d_in[0];  // [16, 64, 65536]
    const float* coords   = (const float*)d_in[1];  // [16, 3, 65536]

    float* grid  = (float*)d_out;                    // [16, 64, 32768]
    float* ncout = grid + (size_t)NB * NC * R3;      // [16, 3, 65536]

    // ws: meanacc[48] | maxn[16] | pad->256B | cnt 2MB | off 2MB | cur 2MB |
    //     voxid 2MB(u16) | sortedvox 2MB(u16, path B only) | sortedfeat 134MB (bf16 rows)
    char* base = (char*)d_ws;
    float* meanacc = (float*)base;
    int*   maxn    = (int*)(base + 192);
    unsigned int*   cnt       = (unsigned int*)(base + 256);
    unsigned int*   off       = cnt + (size_t)NB * R3;
    unsigned int*   cur       = off + (size_t)NB * R3;
    unsigned short* voxid     = (unsigned short*)(cur + (size_t)NB * R3);
    unsigned short* sortedvox = voxid + (size_t)NB * NPTS;   // Path B point-id list
    const size_t sf_off = 256 + 3 * (size_t)NB * R3 * 4 + 2 * (size_t)NB * NPTS * 2;
    unsigned short* sortedfeat = (unsigned short*)(base + sf_off);
    const bool pathA = ws_size >= sf_off + (size_t)NB * NPTS * NC * sizeof(unsigned short);

    // zero meanacc/maxn/cnt (~2 MB). grid memset not needed:
    // voxel_mean2 (path A) / gather_cpt8 (path B) write every element.
    hipMemsetAsync(d_ws, 0, 256 + (size_t)NB * R3 * sizeof(unsigned int), stream);

    mean_partial   <<<NB * 32, 256, 0, stream>>>(coords, meanacc);
    maxnorm_partial<<<NB * 32, 256, 0, stream>>>(coords, meanacc, maxn);
    voxelize       <<<NB * NPTS / 256, 256, 0, stream>>>(coords, meanacc, maxn, ncout, voxid, cnt);
    scan_kernel    <<<NB, 1024, 0, stream>>>(cnt, off, cur);
    if (pathA) {
        transpose_scatter<<<NB * (NPTS / 128), 256, 0, stream>>>(features, voxid, cur, sortedfeat);
        voxel_mean2      <<<NB * 1024 / 4, 256, 0, stream>>>(sortedfeat, off, cnt, grid);
    } else {
        scatter_ids<<<NB * NPTS / 256, 256, 0, stream>>>(voxid, cur, sortedvox);
        gather_cpt8<<<(NB * 8) * (R3 / 256), 256, 0, stream>>>(features, sortedvox, off, cnt, grid);
    }
}

// Round 4
// 749.261 us; speedup vs baseline: 1.2967x; 1.0094x over previous
//
#include <hip/hip_runtime.h>

#define NB   16
#define NC   64
#define NPTS 65536
#define RES  32
#define R3   32768
#define PPB  2048   // points per block in reduction kernels (32 blocks/batch)

typedef unsigned short ushort8 __attribute__((ext_vector_type(8)));
typedef unsigned short ushort2v __attribute__((ext_vector_type(2)));

// ---------------- K1: partial sums for per-batch coord mean ----------------
__global__ void mean_partial(const float* __restrict__ coords, float* __restrict__ meanacc) {
    int bid = blockIdx.x;
    int b = bid >> 5, chunk = bid & 31;
    const float* cb = coords + (size_t)b * 3 * NPTS + chunk * PPB;
    float s0 = 0.f, s1 = 0.f, s2 = 0.f;
    for (int i = threadIdx.x; i < PPB; i += 256) {
        s0 += cb[i];
        s1 += cb[NPTS + i];
        s2 += cb[2 * NPTS + i];
    }
    for (int off = 32; off > 0; off >>= 1) {
        s0 += __shfl_down(s0, off);
        s1 += __shfl_down(s1, off);
        s2 += __shfl_down(s2, off);
    }
    if ((threadIdx.x & 63) == 0) {
        atomicAdd(&meanacc[b * 3 + 0], s0);
        atomicAdd(&meanacc[b * 3 + 1], s1);
        atomicAdd(&meanacc[b * 3 + 2], s2);
    }
}

// ---------------- K2: per-batch max L2 norm (atomicMax on int-reinterpreted float) ----------------
__global__ void maxnorm_partial(const float* __restrict__ coords,
                                const float* __restrict__ meanacc,
                                int* __restrict__ maxn) {
    int bid = blockIdx.x;
    int b = bid >> 5, chunk = bid & 31;
    const float* cb = coords + (size_t)b * 3 * NPTS + chunk * PPB;
    float m0 = meanacc[b * 3 + 0] * (1.0f / NPTS);
    float m1 = meanacc[b * 3 + 1] * (1.0f / NPTS);
    float m2 = meanacc[b * 3 + 2] * (1.0f / NPTS);
    float mx = 0.f;
    for (int i = threadIdx.x; i < PPB; i += 256) {
        float x = cb[i] - m0;
        float y = cb[NPTS + i] - m1;
        float z = cb[2 * NPTS + i] - m2;
        mx = fmaxf(mx, sqrtf(x * x + y * y + z * z));
    }
    for (int off = 32; off > 0; off >>= 1)
        mx = fmaxf(mx, __shfl_down(mx, off));
    if ((threadIdx.x & 63) == 0)
        atomicMax(&maxn[b], __float_as_int(mx));   // norms >= 0: int order == float order
}

// ---------------- K3: normalize coords (2nd output), voxel id, count histogram ----------------
__global__ void voxelize(const float* __restrict__ coords,
                         const float* __restrict__ meanacc,
                         const int* __restrict__ maxn,
                         float* __restrict__ ncout,
                         unsigned short* __restrict__ voxid,
                         unsigned int* __restrict__ cnt) {
    int t = blockIdx.x * 256 + threadIdx.x;
    int b = t >> 16, n = t & (NPTS - 1);
    const float* cb = coords + (size_t)b * 3 * NPTS;
    float m2 = __int_as_float(maxn[b]) * 2.0f;   // EPS = 0
    float c0 = meanacc[b * 3 + 0] * (1.0f / NPTS);
    float c1 = meanacc[b * 3 + 1] * (1.0f / NPTS);
    float c2 = meanacc[b * 3 + 2] * (1.0f / NPTS);
    float ncx = (cb[n]            - c0) / m2 + 0.5f;
    float ncy = (cb[NPTS + n]     - c1) / m2 + 0.5f;
    float ncz = (cb[2 * NPTS + n] - c2) / m2 + 0.5f;
    float sx = fminf(fmaxf(ncx * (float)RES, 0.f), (float)(RES - 1));
    float sy = fminf(fmaxf(ncy * (float)RES, 0.f), (float)(RES - 1));
    float sz = fminf(fmaxf(ncz * (float)RES, 0.f), (float)(RES - 1));
    float* nb = ncout + (size_t)b * 3 * NPTS;
    nb[n]            = sx;
    nb[NPTS + n]     = sy;
    nb[2 * NPTS + n] = sz;
    int v = (((int)rintf(sx)) << 10) + (((int)rintf(sy)) << 5) + (int)rintf(sz);
    voxid[t] = (unsigned short)v;
    atomicAdd(&cnt[((size_t)b << 15) + v], 1u);
}

// ---------------- K4: per-batch exclusive scan of counts -> offsets (+cursor copy) ----------------
__global__ void scan_kernel(const unsigned int* __restrict__ cnt,
                            unsigned int* __restrict__ off,
                            unsigned int* __restrict__ cur) {
    __shared__ unsigned int s[1024];
    int b = blockIdx.x, tid = threadIdx.x;
    const unsigned int* cb = cnt + ((size_t)b << 15);
    int base = tid * 32;
    unsigned int local[32];
    unsigned int sum = 0;
    for (int j = 0; j < 32; ++j) { local[j] = cb[base + j]; sum += local[j]; }
    s[tid] = sum;
    __syncthreads();
    for (int o = 1; o < 1024; o <<= 1) {
        unsigned int t2 = (tid >= o) ? s[tid - o] : 0u;
        __syncthreads();
        s[tid] += t2;
        __syncthreads();
    }
    unsigned int run = s[tid] - sum;   // exclusive base for this thread's chunk
    unsigned int* ob = off + ((size_t)b << 15);
    unsigned int* ub = cur + ((size_t)b << 15);
    for (int j = 0; j < 32; ++j) {
        ob[base + j] = run;
        ub[base + j] = run;
        run += local[j];
    }
}

// ============ PATH A: transpose into voxel-sorted bf16 rows, then chunk-scan ============

// K5a: coalesced-read a 128-point x 64-ch tile, LDS-transpose, write each point's
// 64-ch row (bf16, 128B contiguous) at its voxel-sorted slot; record row's voxel id.
__global__ void transpose_scatter(const float* __restrict__ features,
                                  const unsigned short* __restrict__ voxid,
                                  unsigned int* __restrict__ cur,
                                  unsigned short* __restrict__ sortedfeat,  // bf16 rows
                                  unsigned short* __restrict__ sortedvox) {
    __shared__ float lds[128 * 65];
    __shared__ unsigned int posArr[128];
    int bid = blockIdx.x;                  // 16 * 512 blocks
    int b = bid >> 9;
    int n0 = (bid & 511) << 7;             // 128 points per block
    int pt = threadIdx.x & 127;
    int half = threadIdx.x >> 7;           // 0/1 -> channels 0..31 / 32..63
    const float* fb = features + ((size_t)b << 22) + n0 + pt;
#pragma unroll
    for (int cc = 0; cc < 32; ++cc) {
        int c = (half << 5) + cc;
        lds[pt * 65 + c] = fb[(size_t)c << 16];   // coalesced 512B per (c)
    }
    if (threadIdx.x < 128) {
        int v = voxid[((size_t)b << 16) + n0 + threadIdx.x];
        unsigned int pos = atomicAdd(&cur[((size_t)b << 15) + v], 1u);
        posArr[threadIdx.x] = pos;
        sortedvox[((size_t)b << 16) + pos] = (unsigned short)v;
    }
    __syncthreads();
    int w = threadIdx.x >> 6;              // 4 waves, 32 points each
    int lane = threadIdx.x & 63;
    for (int p = (w << 5); p < (w << 5) + 32; ++p) {
        unsigned int pos = posArr[p];
        float f = lds[p * 65 + lane];
        unsigned int x = __float_as_uint(f);
        unsigned short h = (unsigned short)((x + 0x7fffu + ((x >> 16) & 1u)) >> 16);  // RNE bf16
        sortedfeat[(((size_t)((b << 16) + pos)) << 6) + lane] = h;
    }
}

// K6a: balanced segmented scan. One wave per 128 sorted rows (8192 waves, identical
// work). Stage: lane loads 16x ushort8 (coalesced 1KB/wave-instr) -> ds_write_b128
// into a private LDS tile; vox ids staged alongside. Scan: lane = channel, per row
// one ds_read_u16 (2-way alias = free) + add. Contained-segment count derived from
// the id stream (i - istart) -> direct mean store; spanning segments -> atomicAdd
// into pre-zeroed grid + blist entry owned by the starting chunk.
__global__ void seg_reduce2(const unsigned short* __restrict__ sf,    // bf16 rows
                            const unsigned short* __restrict__ svox,
                            float* __restrict__ grid,                 // pre-zeroed
                            unsigned int* __restrict__ blist,
                            unsigned int* __restrict__ bcount) {
    __shared__ unsigned short s[4][8448];              // per-wave: 8192 row + 128 vox + pad
    int wv   = threadIdx.x >> 6;
    int lane = threadIdx.x & 63;
    int wid  = (blockIdx.x << 2) + wv;                 // 8192 waves
    int b    = wid >> 9;                               // 512 chunks per batch
    int base = (wid & 511) << 7;                       // row base within batch
    const unsigned short* gsrc = sf + ((size_t)b << 22) + ((size_t)base << 6);
    const unsigned short* svb  = svox + ((size_t)b << 16) + base;
    unsigned short* rows = &s[wv][0];
    unsigned short* voxa = &s[wv][8192];

    // stage 128 rows (16KB) + 128 vox ids into this wave's LDS tile
    ushort8 r[16];
#pragma unroll
    for (int j = 0; j < 16; ++j)
        r[j] = *(const ushort8*)(gsrc + (j << 9) + (lane << 3));
    *(ushort2v*)&voxa[lane << 1] = *(const ushort2v*)&svb[lane << 1];
#pragma unroll
    for (int j = 0; j < 16; ++j)
        *(ushort8*)(rows + (j << 9) + (lane << 3)) = r[j];

    int prevvox = (base > 0) ? (int)svb[-1] : -1;
    int nextvox = (base + 128 < NPTS) ? (int)svb[128] : -1;
    float* gb = grid + ((size_t)b << 21);              // b * 64 * 32768

    float acc = 0.f;
    int vcur = voxa[0];
    int istart = 0;
    for (int i = 0; i < 128; ++i) {
        int v = voxa[i];
        if (v != vcur) {                               // wave-uniform
            int count = i - istart;
            bool starts = (istart > 0) || (prevvox != vcur);
            float* gp = gb + ((size_t)lane << 15) + vcur;
            if (starts) *gp = acc / (float)count;      // fully contained
            else        atomicAdd(gp, acc);            // continuation from prev chunk
            acc = 0.f; vcur = v; istart = i;
        }
        acc += __uint_as_float((unsigned int)rows[(i << 6) + lane] << 16);
    }
    {   // tail segment
        int count = 128 - istart;
        bool starts = (istart > 0) || (prevvox != vcur);
        bool ends   = (nextvox != vcur);
        float* gp = gb + ((size_t)lane << 15) + vcur;
        if (starts && ends) {
            *gp = acc / (float)count;
        } else {
            atomicAdd(gp, acc);
            if (starts && lane == 0) {                 // exactly one chunk owns the start
                unsigned int p = atomicAdd(bcount, 1u);
                blist[p] = ((unsigned int)b << 15) | (unsigned int)vcur;
            }
        }
    }
}

// K7a: divide the boundary voxels (sums) by their counts.
__global__ void fix_boundary(const unsigned int* __restrict__ blist,
                             const unsigned int* __restrict__ bcount,
                             const unsigned int* __restrict__ cnt,
                             float* __restrict__ grid) {
    int w = (blockIdx.x * 256 + threadIdx.x) >> 6;     // 8192 waves max
    int lane = threadIdx.x & 63;
    if ((unsigned int)w >= *bcount) return;
    unsigned int e = blist[w];
    int b = e >> 15, v = e & (R3 - 1);
    float k = (float)cnt[((size_t)b << 15) + v];
    size_t idx = (((size_t)((b << 6) + lane)) << 15) + v;
    grid[idx] = grid[idx] / fmaxf(k, 1.0f);
}

// ============ PATH B (fallback, small ws): sorted-index gather with 8-ch ILP ============

__global__ void scatter_ids(const unsigned short* __restrict__ voxid,
                            unsigned int* __restrict__ cur,
                            unsigned short* __restrict__ sorted) {
    int t = blockIdx.x * 256 + threadIdx.x;
    int b = t >> 16, n = t & (NPTS - 1);
    int v = voxid[t];
    unsigned int pos = atomicAdd(&cur[((size_t)b << 15) + v], 1u);
    sorted[((size_t)b << 16) + pos] = (unsigned short)n;
}

__global__ void gather_cpt8(const float* __restrict__ features,
                            const unsigned short* __restrict__ sorted,
                            const unsigned int* __restrict__ off,
                            const unsigned int* __restrict__ cnt,
                            float* __restrict__ grid) {
    int bid = blockIdx.x;
    int xcd = bid & 7;
    int g_  = bid >> 3;
    int chunk = g_ & 127;
    int sgg = g_ >> 7;
    int sg = (sgg << 3) + xcd;
    int b = sg >> 3;
    int c0 = (sg & 7) << 3;
    int v = (chunk << 8) + threadIdx.x;
    size_t bv = ((size_t)b << 15) + v;
    unsigned int base = off[bv];
    unsigned int k = cnt[bv];
    const unsigned short* sp = sorted + ((size_t)b << 16);
    const float* f = features + ((size_t)((b << 6) + c0) << 16);
    float s[8] = {0,0,0,0,0,0,0,0};
    for (unsigned int i = 0; i < k; ++i) {
        int idx = sp[base + i];
#pragma unroll
        for (int j = 0; j < 8; ++j)
            s[j] += f[((size_t)j << 16) + idx];
    }
    float inv = 1.0f / fmaxf((float)k, 1.0f);
#pragma unroll
    for (int j = 0; j < 8; ++j)
        grid[((size_t)((b << 6) + c0 + j) << 15) + v] = s[j] * inv;
}

extern "C" void kernel_launch(void* const* d_in, const int* in_sizes, int n_in,
                              void* d_out, int out_size, void* d_ws, size_t ws_size,
                              hipStream_t stream) {
    const float* features = (const float*)d_in[0];  // [16, 64, 65536]
    const float* coords   = (const float*)d_in[1];  // [16, 3, 65536]

    float* grid  = (float*)d_out;                    // [16, 64, 32768]
    float* ncout = grid + (size_t)NB * NC * R3;      // [16, 3, 65536]

    // ws: meanacc[48] | maxn[16] | pad->256B | cnt 2MB | off 2MB | cur 2MB |
    //     voxid 2MB(u16) | sortedvox 2MB(u16) | sortedfeat 134MB (bf16 rows)
    char* base = (char*)d_ws;
    float* meanacc = (float*)base;
    int*   maxn    = (int*)(base + 192);
    unsigned int*   cnt       = (unsigned int*)(base + 256);
    unsigned int*   off       = cnt + (size_t)NB * R3;
    unsigned int*   cur       = off + (size_t)NB * R3;
    unsigned short* voxid     = (unsigned short*)(cur + (size_t)NB * R3);
    unsigned short* sortedvox = voxid + (size_t)NB * NPTS;   // Path B reuses as point-id list
    const size_t sf_off = 256 + 3 * (size_t)NB * R3 * 4 + 2 * (size_t)NB * NPTS * 2;
    unsigned short* sortedfeat = (unsigned short*)(base + sf_off);
    const bool pathA = ws_size >= sf_off + (size_t)NB * NPTS * NC * sizeof(unsigned short);

    // cur region is dead after transpose_scatter: reuse for bcount + boundary list
    unsigned int* bcount = cur;
    unsigned int* blist  = cur + 64;

    // zero meanacc/maxn/cnt (~2 MB) and the grid accumulator (128 MB, atomic targets + empties)
    hipMemsetAsync(d_ws, 0, 256 + (size_t)NB * R3 * sizeof(unsigned int), stream);
    hipMemsetAsync(d_out, 0, (size_t)NB * NC * R3 * sizeof(float), stream);

    mean_partial   <<<NB * 32, 256, 0, stream>>>(coords, meanacc);
    maxnorm_partial<<<NB * 32, 256, 0, stream>>>(coords, meanacc, maxn);
    voxelize       <<<NB * NPTS / 256, 256, 0, stream>>>(coords, meanacc, maxn, ncout, voxid, cnt);
    scan_kernel    <<<NB, 1024, 0, stream>>>(cnt, off, cur);
    if (pathA) {
        transpose_scatter<<<NB * (NPTS / 128), 256, 0, stream>>>(features, voxid, cur,
                                                                 sortedfeat, sortedvox);
        hipMemsetAsync(bcount, 0, sizeof(unsigned int), stream);   // cur dead now
        seg_reduce2  <<<NB * (NPTS / 128) / 4, 256, 0, stream>>>(sortedfeat, sortedvox,
                                                                 grid, blist, bcount);
        fix_boundary <<<2048, 256, 0, stream>>>(blist, bcount, cnt, grid);
    } else {
        scatter_ids<<<NB * NPTS / 256, 256, 0, stream>>>(voxid, cur, sortedvox);
        gather_cpt8<<<(NB * 8) * (R3 / 256), 256, 0, stream>>>(features, sortedvox, off, cnt, grid);
    }
}